// Round 4
// baseline (422.424 us; speedup 1.0000x reference)
//
#include <hip/hip_runtime.h>

#define K7   7
#define PAD3 3
#define C64  64
#define CRED 32          // C/2
#define GC4  4
#define EPSV 1e-5f

#define TILE 8                      // 8x8 pixels per block
#define HALO 14                     // TILE + K7 - 1
#define NPIX (HALO * HALO)          // 196
#define NCH  32                     // y-channels per block (half of 64)
#define NSL  8                      // channel-groups (slots) per block
#define TSTH 40                     // t_lds row stride in f16 (80B, 16B-aligned)

typedef _Float16 half8 __attribute__((ext_vector_type(8)));
typedef float    f32x4 __attribute__((ext_vector_type(4)));

__global__ __launch_bounds__(256, 4)
void involution_mfma(const float* __restrict__ x, const float* __restrict__ y,
                     const float* __restrict__ w1, const float* __restrict__ b1,
                     const float* __restrict__ gma, const float* __restrict__ bta,
                     const float* __restrict__ mu,  const float* __restrict__ var,
                     const float* __restrict__ w2,  const float* __restrict__ b2,
                     float* __restrict__ out)
{
    // [pixel][slot][4ch], slot rotated by pixel: ch-group cg stored at slot (cg+pix)&7
    __shared__ __align__(16) float    ytile[NPIX * NCH];   // 25088 B
    __shared__ __align__(16) _Float16 t_lds[64 * TSTH];    //  5120 B

    const int tid = threadIdx.x;
    const int bx = blockIdx.x, by = blockIdx.y, bz = blockIdx.z;
    const int b = bz >> 1, half = bz & 1;
    const int gh0 = by * TILE, gw0 = bx * TILE;
    const int c0 = half * NCH;

    // ---- stage y halo tile: 32 ch x 14 x 14, swizzled channel-inner layout ----
    for (int li = tid; li < NCH * NPIX; li += 256) {
        int c    = li / NPIX;
        int pixl = li - c * NPIX;
        int rr   = pixl / HALO;
        int col  = pixl - rr * HALO;
        int grow = gh0 - PAD3 + rr;
        int gcol = gw0 - PAD3 + col;
        float v = 0.f;
        if ((unsigned)grow < 128u && (unsigned)gcol < 128u)
            v = y[((size_t)(b * C64 + c0 + c) << 14) + (grow << 7) + gcol];
        int slot = ((c >> 2) + pixl) & 7;
        ytile[pixl * NCH + slot * 4 + (c & 3)] = v;
    }

    // ---- phase 1: conv1 (1x1) + BN(eval) + ReLU -> t_lds as f16 [pixel][k] ----
    const int p  = tid & 63;                   // pixel within 8x8 tile (== lane)
    const int ph = p >> 3, pw = p & 7;
    const int oq = __builtin_amdgcn_readfirstlane(tid >> 6);  // wave id, uniform
    const int pix = ((gh0 + ph) << 7) + (gw0 + pw);
    {
        float dot[8] = {0,0,0,0,0,0,0,0};
        const float* w1q = w1 + oq * 8 * C64;
        const float* xp  = x + ((size_t)(b * C64) << 14) + pix;
        #pragma unroll 8
        for (int c = 0; c < C64; ++c) {
            float xc = xp[(size_t)c << 14];
            #pragma unroll
            for (int j = 0; j < 8; ++j) dot[j] += w1q[j * C64 + c] * xc;
        }
        _Float16 tv16[8];
        #pragma unroll
        for (int j = 0; j < 8; ++j) {
            int o = oq * 8 + j;
            float sv = gma[o] * rsqrtf(var[o] + EPSV);
            float bb = (b1[o] - mu[o]) * sv + bta[o];
            tv16[j] = (_Float16)fmaxf(dot[j] * sv + bb, 0.f);
        }
        *(half8*)&t_lds[p * TSTH + oq * 8] = *(const half8*)tv16;
    }
    __syncthreads();

    // ---- phase 2: MFMA conv2 + depthwise aggregation ----
    const int q = p >> 4;          // lane quadrant
    const int r = p & 15;

    // B fragments: B[k][col=pixel], lane holds k = 8q..8q+7, col = 16nt + r
    half8 bfrag0 = *(const half8*)&t_lds[( 0 + r) * TSTH + q * 8];
    half8 bfrag1 = *(const half8*)&t_lds[(16 + r) * TSTH + q * 8];
    half8 bfrag2 = *(const half8*)&t_lds[(32 + r) * TSTH + q * 8];
    half8 bfrag3 = *(const half8*)&t_lds[(48 + r) * TSTH + q * 8];

    const int pb0 = (0 + (r >> 3)) * HALO + (r & 7);
    const int pb1 = (2 + (r >> 3)) * HALO + (r & 7);
    const int pb2 = (4 + (r >> 3)) * HALO + (r & 7);
    const int pb3 = (6 + (r >> 3)) * HALO + (r & 7);

    const f32x4 zero = {0.f, 0.f, 0.f, 0.f};

    #pragma unroll 1
    for (int lgi = 0; lgi < 2; ++lgi) {
        const int lg = oq * 2 + lgi;           // local group 0..7 (wave-uniform)
        const int g  = half * NSL + lg;        // global group 0..15
        const float* w2g = w2 + g * 49 * CRED;
        const float* b2g = b2 + g * 49;

        float acc[4][4];                       // [nt][channel], all const-indexed
        #pragma unroll
        for (int nt = 0; nt < 4; ++nt)
            #pragma unroll
            for (int c = 0; c < 4; ++c) acc[nt][c] = 0.f;

        // ---- mt = 0..2 : rows mt*16 + r <= 47, all < 49 -> unconditional ----
        #pragma unroll
        for (int mt = 0; mt < 3; ++mt) {
            half8 af;
            {
                const float* wr = w2g + (mt * 16 + r) * CRED + q * 8;
                float4 wa = *(const float4*)wr;
                float4 wb = *(const float4*)(wr + 4);
                af[0] = (_Float16)wa.x; af[1] = (_Float16)wa.y;
                af[2] = (_Float16)wa.z; af[3] = (_Float16)wa.w;
                af[4] = (_Float16)wb.x; af[5] = (_Float16)wb.y;
                af[6] = (_Float16)wb.z; af[7] = (_Float16)wb.w;
            }
            f32x4 d0 = __builtin_amdgcn_mfma_f32_16x16x32_f16(af, bfrag0, zero, 0, 0, 0);
            f32x4 d1 = __builtin_amdgcn_mfma_f32_16x16x32_f16(af, bfrag1, zero, 0, 0, 0);
            f32x4 d2 = __builtin_amdgcn_mfma_f32_16x16x32_f16(af, bfrag2, zero, 0, 0, 0);
            f32x4 d3 = __builtin_amdgcn_mfma_f32_16x16x32_f16(af, bfrag3, zero, 0, 0, 0);

            #pragma unroll
            for (int reg = 0; reg < 4; ++reg) {
                const int tap = mt * 16 + q * 4 + reg;     // lane's tap, < 49
                const float bv = b2g[tap];
                const int di = (tap * 9363) >> 16;         // tap / 7
                const int tapoff = tap + 7 * di;           // di*14 + dj
                {
                    float wv = d0[reg] + bv;
                    int tp2 = pb0 + tapoff;
                    const float4 y4 = *(const float4*)&ytile[tp2 * NCH + (((lg + tp2) & 7) << 2)];
                    acc[0][0] += wv * y4.x; acc[0][1] += wv * y4.y;
                    acc[0][2] += wv * y4.z; acc[0][3] += wv * y4.w;
                }
                {
                    float wv = d1[reg] + bv;
                    int tp2 = pb1 + tapoff;
                    const float4 y4 = *(const float4*)&ytile[tp2 * NCH + (((lg + tp2) & 7) << 2)];
                    acc[1][0] += wv * y4.x; acc[1][1] += wv * y4.y;
                    acc[1][2] += wv * y4.z; acc[1][3] += wv * y4.w;
                }
                {
                    float wv = d2[reg] + bv;
                    int tp2 = pb2 + tapoff;
                    const float4 y4 = *(const float4*)&ytile[tp2 * NCH + (((lg + tp2) & 7) << 2)];
                    acc[2][0] += wv * y4.x; acc[2][1] += wv * y4.y;
                    acc[2][2] += wv * y4.z; acc[2][3] += wv * y4.w;
                }
                {
                    float wv = d3[reg] + bv;
                    int tp2 = pb3 + tapoff;
                    const float4 y4 = *(const float4*)&ytile[tp2 * NCH + (((lg + tp2) & 7) << 2)];
                    acc[3][0] += wv * y4.x; acc[3][1] += wv * y4.y;
                    acc[3][2] += wv * y4.z; acc[3][3] += wv * y4.w;
                }
            }
        }

        // ---- mt = 3 : only tap 48 is real (q==0, reg==0) ----
        {
            half8 af;
            #pragma unroll
            for (int j = 0; j < 8; ++j) af[j] = (_Float16)0.f;
            if (r == 0) {
                const float* wr = w2g + 48 * CRED + q * 8;
                float4 wa = *(const float4*)wr;
                float4 wb = *(const float4*)(wr + 4);
                af[0] = (_Float16)wa.x; af[1] = (_Float16)wa.y;
                af[2] = (_Float16)wa.z; af[3] = (_Float16)wa.w;
                af[4] = (_Float16)wb.x; af[5] = (_Float16)wb.y;
                af[6] = (_Float16)wb.z; af[7] = (_Float16)wb.w;
            }
            f32x4 d0 = __builtin_amdgcn_mfma_f32_16x16x32_f16(af, bfrag0, zero, 0, 0, 0);
            f32x4 d1 = __builtin_amdgcn_mfma_f32_16x16x32_f16(af, bfrag1, zero, 0, 0, 0);
            f32x4 d2 = __builtin_amdgcn_mfma_f32_16x16x32_f16(af, bfrag2, zero, 0, 0, 0);
            f32x4 d3 = __builtin_amdgcn_mfma_f32_16x16x32_f16(af, bfrag3, zero, 0, 0, 0);

            const float bv = b2g[48];
            const int tapoff = 48 + 7 * 6;                 // 90, uniform
            const bool live = (q == 0);
            {
                float wv = live ? (d0[0] + bv) : 0.f;
                int tp2 = pb0 + tapoff;
                const float4 y4 = *(const float4*)&ytile[tp2 * NCH + (((lg + tp2) & 7) << 2)];
                acc[0][0] += wv * y4.x; acc[0][1] += wv * y4.y;
                acc[0][2] += wv * y4.z; acc[0][3] += wv * y4.w;
            }
            {
                float wv = live ? (d1[0] + bv) : 0.f;
                int tp2 = pb1 + tapoff;
                const float4 y4 = *(const float4*)&ytile[tp2 * NCH + (((lg + tp2) & 7) << 2)];
                acc[1][0] += wv * y4.x; acc[1][1] += wv * y4.y;
                acc[1][2] += wv * y4.z; acc[1][3] += wv * y4.w;
            }
            {
                float wv = live ? (d2[0] + bv) : 0.f;
                int tp2 = pb2 + tapoff;
                const float4 y4 = *(const float4*)&ytile[tp2 * NCH + (((lg + tp2) & 7) << 2)];
                acc[2][0] += wv * y4.x; acc[2][1] += wv * y4.y;
                acc[2][2] += wv * y4.z; acc[2][3] += wv * y4.w;
            }
            {
                float wv = live ? (d3[0] + bv) : 0.f;
                int tp2 = pb3 + tapoff;
                const float4 y4 = *(const float4*)&ytile[tp2 * NCH + (((lg + tp2) & 7) << 2)];
                acc[3][0] += wv * y4.x; acc[3][1] += wv * y4.y;
                acc[3][2] += wv * y4.z; acc[3][3] += wv * y4.w;
            }
        }

        // reduce partial sums across quadrants (each quadrant covered a tap subset)
        #pragma unroll
        for (int nt = 0; nt < 4; ++nt)
            #pragma unroll
            for (int c = 0; c < 4; ++c) {
                float v = acc[nt][c];
                v += __shfl_xor(v, 16);
                v += __shfl_xor(v, 32);
                acc[nt][c] = v;
            }

        // lane p stores pixel p (= 16*q + r, i.e. nt = q)
        size_t ob = ((size_t)(b * C64 + g * GC4) << 14) + pix;
        #pragma unroll
        for (int c = 0; c < 4; ++c) {
            float s0 = (q & 1) ? acc[1][c] : acc[0][c];
            float s1 = (q & 1) ? acc[3][c] : acc[2][c];
            float vv = (q & 2) ? s1 : s0;
            out[ob + ((size_t)c << 14)] = vv;
        }
    }
}

extern "C" void kernel_launch(void* const* d_in, const int* in_sizes, int n_in,
                              void* d_out, int out_size, void* d_ws, size_t ws_size,
                              hipStream_t stream) {
    const float* x   = (const float*)d_in[0];
    const float* y   = (const float*)d_in[1];
    const float* w1  = (const float*)d_in[2];
    const float* b1  = (const float*)d_in[3];
    const float* gma = (const float*)d_in[4];
    const float* bta = (const float*)d_in[5];
    const float* mu  = (const float*)d_in[6];
    const float* var = (const float*)d_in[7];
    const float* w2  = (const float*)d_in[8];
    const float* b2  = (const float*)d_in[9];
    float* out = (float*)d_out;

    dim3 grid(128 / TILE, 128 / TILE, 8);   // 16 x 16 x (4 batch * 2 halves)
    dim3 block(256);
    hipLaunchKernelGGL(involution_mfma, grid, block, 0, stream,
                       x, y, w1, b1, gma, bta, mu, var, w2, b2, out);
}

// Round 5
// 187.972 us; speedup vs baseline: 2.2473x; 2.2473x over previous
//
#include <hip/hip_runtime.h>

#define K7   7
#define PAD3 3
#define C64  64
#define CRED 32          // C/2
#define GC4  4
#define EPSV 1e-5f

#define TILE 8                      // 8x8 pixels per block
#define HALO 14                     // TILE + K7 - 1
#define NPIX (HALO * HALO)          // 196
#define NCH  32                     // y-channels per block (half of 64)
#define NSL  8                      // channel-groups per block
#define TSTH 40                     // t_lds row stride in f16 (80B, 16B-aligned)
#define W2ST 40                     // w2_lds row stride in f16
#define W2G  (49 * W2ST)            // 1960 f16 per group

typedef _Float16 half8 __attribute__((ext_vector_type(8)));
typedef _Float16 half4 __attribute__((ext_vector_type(4)));
typedef float    f32x4 __attribute__((ext_vector_type(4)));

__global__ __launch_bounds__(256, 2)
void involution_mfma(const float* __restrict__ x, const float* __restrict__ y,
                     const float* __restrict__ w1, const float* __restrict__ b1,
                     const float* __restrict__ gma, const float* __restrict__ bta,
                     const float* __restrict__ mu,  const float* __restrict__ var,
                     const float* __restrict__ w2,  const float* __restrict__ b2,
                     float* __restrict__ out)
{
    // ytile: [pixel][slot][4ch], slot rotated: ch-group cg stored at slot (cg+pix)&7
    __shared__ __align__(16) float    ytile[NPIX * NCH];    // 25088 B
    __shared__ __align__(16) _Float16 t_lds[64 * TSTH];     //  5120 B
    __shared__ __align__(16) _Float16 w2h[NSL * W2G];       // 31360 B
    __shared__            float    bias_l[NSL * 49];        //  1568 B

    const int tid = threadIdx.x;
    const int bx = blockIdx.x, by = blockIdx.y, bz = blockIdx.z;
    const int b = bz >> 1, half = bz & 1;
    const int gh0 = by * TILE, gw0 = bx * TILE;
    const int c0 = half * NCH;

    // ---- stage y halo tile: 32 ch x 14 x 14, swizzled channel-inner layout ----
    for (int li = tid; li < NCH * NPIX; li += 256) {
        int c    = li / NPIX;
        int pixl = li - c * NPIX;
        int rr   = pixl / HALO;
        int col  = pixl - rr * HALO;
        int grow = gh0 - PAD3 + rr;
        int gcol = gw0 - PAD3 + col;
        float v = 0.f;
        if ((unsigned)grow < 128u && (unsigned)gcol < 128u)
            v = y[((size_t)(b * C64 + c0 + c) << 14) + (grow << 7) + gcol];
        int slot = ((c >> 2) + pixl) & 7;
        ytile[pixl * NCH + slot * 4 + (c & 3)] = v;
    }

    // ---- stage w2 -> LDS as f16 [group][row(49) x stride 40] ----
    // unit = 4 consecutive k values; 8 groups * 49 rows * 8 units = 3136 units
    for (int u = tid; u < NSL * 49 * 8; u += 256) {
        int gl  = u / 392;                 // 49*8
        int rem = u - gl * 392;
        int row = rem >> 3;
        int k4  = (rem & 7) << 2;
        const float4 w4 = *(const float4*)&w2[(((half * NSL + gl) * 49 + row) << 5) + k4];
        half4 h;
        h[0] = (_Float16)w4.x; h[1] = (_Float16)w4.y;
        h[2] = (_Float16)w4.z; h[3] = (_Float16)w4.w;
        *(half4*)&w2h[gl * W2G + row * W2ST + k4] = h;
    }
    // ---- stage b2 -> LDS ----
    for (int li = tid; li < NSL * 49; li += 256) {
        int gl = li / 49, tap = li - gl * 49;
        bias_l[li] = b2[(half * NSL + gl) * 49 + tap];
    }

    // ---- phase 1: conv1 (1x1) + BN(eval) + ReLU -> t_lds as f16 [pixel][k] ----
    const int p  = tid & 63;                   // pixel within 8x8 tile (== lane)
    const int ph = p >> 3, pw = p & 7;
    const int oq = __builtin_amdgcn_readfirstlane(tid >> 6);  // wave id, uniform
    const int pix = ((gh0 + ph) << 7) + (gw0 + pw);
    {
        float dot[8] = {0,0,0,0,0,0,0,0};
        const float* w1q = w1 + oq * 8 * C64;
        const float* xp  = x + ((size_t)(b * C64) << 14) + pix;
        #pragma unroll 8
        for (int c = 0; c < C64; ++c) {
            float xc = xp[(size_t)c << 14];
            #pragma unroll
            for (int j = 0; j < 8; ++j) dot[j] += w1q[j * C64 + c] * xc;
        }
        _Float16 tv16[8];
        #pragma unroll
        for (int j = 0; j < 8; ++j) {
            int o = oq * 8 + j;
            float sv = gma[o] * rsqrtf(var[o] + EPSV);
            float bb = (b1[o] - mu[o]) * sv + bta[o];
            tv16[j] = (_Float16)fmaxf(dot[j] * sv + bb, 0.f);
        }
        *(half8*)&t_lds[p * TSTH + oq * 8] = *(const half8*)tv16;
    }
    __syncthreads();

    // ---- phase 2: MFMA conv2 + depthwise aggregation ----
    const int q = p >> 4;          // lane quadrant
    const int r = p & 15;

    // B fragments: B[k][col=pixel], lane holds k = 8q..8q+7, col = 16nt + r
    half8 bfrag0 = *(const half8*)&t_lds[( 0 + r) * TSTH + q * 8];
    half8 bfrag1 = *(const half8*)&t_lds[(16 + r) * TSTH + q * 8];
    half8 bfrag2 = *(const half8*)&t_lds[(32 + r) * TSTH + q * 8];
    half8 bfrag3 = *(const half8*)&t_lds[(48 + r) * TSTH + q * 8];

    const int pb0 = (0 + (r >> 3)) * HALO + (r & 7);
    const int pb1 = (2 + (r >> 3)) * HALO + (r & 7);
    const int pb2 = (4 + (r >> 3)) * HALO + (r & 7);
    const int pb3 = (6 + (r >> 3)) * HALO + (r & 7);

    const f32x4 zero = {0.f, 0.f, 0.f, 0.f};

    #pragma unroll 1
    for (int lgi = 0; lgi < 2; ++lgi) {
        const int lg = oq * 2 + lgi;           // local group 0..7 (wave-uniform)
        const int g  = half * NSL + lg;        // global group 0..15
        const _Float16* w2hg = w2h + lg * W2G;
        const float*    blg  = bias_l + lg * 49;

        float acc[4][4];                       // [nt][channel], const-indexed only
        #pragma unroll
        for (int nt = 0; nt < 4; ++nt)
            #pragma unroll
            for (int c = 0; c < 4; ++c) acc[nt][c] = 0.f;

        // ---- mt = 0..2 : rows mt*16 + r <= 47 all real ----
        #pragma unroll
        for (int mt = 0; mt < 3; ++mt) {
            const half8 af = *(const half8*)&w2hg[(mt * 16 + r) * W2ST + q * 8];

            f32x4 d0 = __builtin_amdgcn_mfma_f32_16x16x32_f16(af, bfrag0, zero, 0, 0, 0);
            f32x4 d1 = __builtin_amdgcn_mfma_f32_16x16x32_f16(af, bfrag1, zero, 0, 0, 0);
            f32x4 d2 = __builtin_amdgcn_mfma_f32_16x16x32_f16(af, bfrag2, zero, 0, 0, 0);
            f32x4 d3 = __builtin_amdgcn_mfma_f32_16x16x32_f16(af, bfrag3, zero, 0, 0, 0);

            #pragma unroll
            for (int reg = 0; reg < 4; ++reg) {
                const int tap = mt * 16 + q * 4 + reg;     // lane's tap, < 49
                const float bv = blg[tap];
                const int di = (tap * 9363) >> 16;         // tap / 7
                const int tapoff = tap + 7 * di;           // di*14 + dj
                {
                    float wv = d0[reg] + bv;
                    int tp2 = pb0 + tapoff;
                    const float4 y4 = *(const float4*)&ytile[tp2 * NCH + (((lg + tp2) & 7) << 2)];
                    acc[0][0] += wv * y4.x; acc[0][1] += wv * y4.y;
                    acc[0][2] += wv * y4.z; acc[0][3] += wv * y4.w;
                }
                {
                    float wv = d1[reg] + bv;
                    int tp2 = pb1 + tapoff;
                    const float4 y4 = *(const float4*)&ytile[tp2 * NCH + (((lg + tp2) & 7) << 2)];
                    acc[1][0] += wv * y4.x; acc[1][1] += wv * y4.y;
                    acc[1][2] += wv * y4.z; acc[1][3] += wv * y4.w;
                }
                {
                    float wv = d2[reg] + bv;
                    int tp2 = pb2 + tapoff;
                    const float4 y4 = *(const float4*)&ytile[tp2 * NCH + (((lg + tp2) & 7) << 2)];
                    acc[2][0] += wv * y4.x; acc[2][1] += wv * y4.y;
                    acc[2][2] += wv * y4.z; acc[2][3] += wv * y4.w;
                }
                {
                    float wv = d3[reg] + bv;
                    int tp2 = pb3 + tapoff;
                    const float4 y4 = *(const float4*)&ytile[tp2 * NCH + (((lg + tp2) & 7) << 2)];
                    acc[3][0] += wv * y4.x; acc[3][1] += wv * y4.y;
                    acc[3][2] += wv * y4.z; acc[3][3] += wv * y4.w;
                }
            }
        }

        // ---- mt = 3 : only tap 48 real (lane r==0 holds row 48; q==0,reg==0 output)
        {
            half8 af = *(const half8*)&w2hg[48 * W2ST + q * 8];   // broadcast read
            if (r != 0) {
                #pragma unroll
                for (int j = 0; j < 8; ++j) af[j] = (_Float16)0.f;
            }
            f32x4 d0 = __builtin_amdgcn_mfma_f32_16x16x32_f16(af, bfrag0, zero, 0, 0, 0);
            f32x4 d1 = __builtin_amdgcn_mfma_f32_16x16x32_f16(af, bfrag1, zero, 0, 0, 0);
            f32x4 d2 = __builtin_amdgcn_mfma_f32_16x16x32_f16(af, bfrag2, zero, 0, 0, 0);
            f32x4 d3 = __builtin_amdgcn_mfma_f32_16x16x32_f16(af, bfrag3, zero, 0, 0, 0);

            const float bv = blg[48];
            const int tapoff = 48 + 7 * 6;                 // 90, uniform
            const bool live = (q == 0);
            {
                float wv = live ? (d0[0] + bv) : 0.f;
                int tp2 = pb0 + tapoff;
                const float4 y4 = *(const float4*)&ytile[tp2 * NCH + (((lg + tp2) & 7) << 2)];
                acc[0][0] += wv * y4.x; acc[0][1] += wv * y4.y;
                acc[0][2] += wv * y4.z; acc[0][3] += wv * y4.w;
            }
            {
                float wv = live ? (d1[0] + bv) : 0.f;
                int tp2 = pb1 + tapoff;
                const float4 y4 = *(const float4*)&ytile[tp2 * NCH + (((lg + tp2) & 7) << 2)];
                acc[1][0] += wv * y4.x; acc[1][1] += wv * y4.y;
                acc[1][2] += wv * y4.z; acc[1][3] += wv * y4.w;
            }
            {
                float wv = live ? (d2[0] + bv) : 0.f;
                int tp2 = pb2 + tapoff;
                const float4 y4 = *(const float4*)&ytile[tp2 * NCH + (((lg + tp2) & 7) << 2)];
                acc[2][0] += wv * y4.x; acc[2][1] += wv * y4.y;
                acc[2][2] += wv * y4.z; acc[2][3] += wv * y4.w;
            }
            {
                float wv = live ? (d3[0] + bv) : 0.f;
                int tp2 = pb3 + tapoff;
                const float4 y4 = *(const float4*)&ytile[tp2 * NCH + (((lg + tp2) & 7) << 2)];
                acc[3][0] += wv * y4.x; acc[3][1] += wv * y4.y;
                acc[3][2] += wv * y4.z; acc[3][3] += wv * y4.w;
            }
        }

        // reduce partial sums across quadrants (each quadrant covered a tap subset)
        #pragma unroll
        for (int nt = 0; nt < 4; ++nt)
            #pragma unroll
            for (int c = 0; c < 4; ++c) {
                float v = acc[nt][c];
                v += __shfl_xor(v, 16);
                v += __shfl_xor(v, 32);
                acc[nt][c] = v;
            }

        // lane p stores pixel p (= 16*q + r, i.e. nt = q)
        size_t ob = ((size_t)(b * C64 + g * GC4) << 14) + pix;
        #pragma unroll
        for (int c = 0; c < 4; ++c) {
            float s0 = (q & 1) ? acc[1][c] : acc[0][c];
            float s1 = (q & 1) ? acc[3][c] : acc[2][c];
            float vv = (q & 2) ? s1 : s0;
            out[ob + ((size_t)c << 14)] = vv;
        }
    }
}

extern "C" void kernel_launch(void* const* d_in, const int* in_sizes, int n_in,
                              void* d_out, int out_size, void* d_ws, size_t ws_size,
                              hipStream_t stream) {
    const float* x   = (const float*)d_in[0];
    const float* y   = (const float*)d_in[1];
    const float* w1  = (const float*)d_in[2];
    const float* b1  = (const float*)d_in[3];
    const float* gma = (const float*)d_in[4];
    const float* bta = (const float*)d_in[5];
    const float* mu  = (const float*)d_in[6];
    const float* var = (const float*)d_in[7];
    const float* w2  = (const float*)d_in[8];
    const float* b2  = (const float*)d_in[9];
    float* out = (float*)d_out;

    dim3 grid(128 / TILE, 128 / TILE, 8);   // 16 x 16 x (4 batch * 2 halves)
    dim3 block(256);
    hipLaunchKernelGGL(involution_mfma, grid, block, 0, stream,
                       x, y, w1, b1, gma, bta, mu, var, w2, b2, out);
}

// Round 6
// 60.798 us; speedup vs baseline: 6.9480x; 3.0917x over previous
//
#include <hip/hip_runtime.h>

#define K7   7
#define PAD3 3
#define C64  64
#define CRED 32          // C/2
#define GC4  4
#define EPSV 1e-5f

#define TILE 8                      // 8x8 pixels per block
#define HALO 14                     // TILE + K7 - 1
#define NPIX (HALO * HALO)          // 196
#define NCH  32                     // y-channels per block (half of 64)
#define NSL  8                      // channel-groups per block
#define TSTH 40                     // t_lds row stride in f16 (80B, 16B-aligned)

typedef _Float16 half8 __attribute__((ext_vector_type(8)));
typedef float    f32x4 __attribute__((ext_vector_type(4)));

__global__ __launch_bounds__(256, 2)
void involution_mfma(const float* __restrict__ x, const float* __restrict__ y,
                     const float* __restrict__ w1, const float* __restrict__ b1,
                     const float* __restrict__ gma, const float* __restrict__ bta,
                     const float* __restrict__ mu,  const float* __restrict__ var,
                     const float* __restrict__ w2,  const float* __restrict__ b2,
                     float* __restrict__ out)
{
    // ytile: [pixel][slot][4ch], slot rotated: ch-group cg stored at slot (cg+pix)&7
    __shared__ __align__(16) float    ytile[NPIX * NCH];   // 25088 B
    __shared__ __align__(16) _Float16 t_lds[64 * TSTH];    //  5120 B

    const int tid = threadIdx.x;
    const int bx = blockIdx.x, by = blockIdx.y, bz = blockIdx.z;
    const int b = bz >> 1, half = bz & 1;
    const int gh0 = by * TILE, gw0 = bx * TILE;
    const int c0 = half * NCH;

    // ---- stage y halo tile: 32 ch x 14 x 14, swizzled channel-inner layout ----
    for (int li = tid; li < NCH * NPIX; li += 256) {
        int c    = li / NPIX;
        int pixl = li - c * NPIX;
        int rr   = pixl / HALO;
        int col  = pixl - rr * HALO;
        int grow = gh0 - PAD3 + rr;
        int gcol = gw0 - PAD3 + col;
        float v = 0.f;
        if ((unsigned)grow < 128u && (unsigned)gcol < 128u)
            v = y[((size_t)(b * C64 + c0 + c) << 14) + (grow << 7) + gcol];
        int slot = ((c >> 2) + pixl) & 7;
        ytile[pixl * NCH + slot * 4 + (c & 3)] = v;
    }

    // ---- phase 1: conv1 (1x1) + BN(eval) + ReLU -> t_lds as f16 [pixel][k] ----
    const int p  = tid & 63;                   // pixel within 8x8 tile (== lane)
    const int ph = p >> 3, pw = p & 7;
    const int oq = __builtin_amdgcn_readfirstlane(tid >> 6);  // wave id, uniform
    const int pix = ((gh0 + ph) << 7) + (gw0 + pw);
    {
        float dot[8] = {0,0,0,0,0,0,0,0};
        const float* w1q = w1 + oq * 8 * C64;
        const float* xp  = x + ((size_t)(b * C64) << 14) + pix;
        #pragma unroll 8
        for (int c = 0; c < C64; ++c) {
            float xc = xp[(size_t)c << 14];
            #pragma unroll
            for (int j = 0; j < 8; ++j) dot[j] += w1q[j * C64 + c] * xc;
        }
        _Float16 tv16[8];
        #pragma unroll
        for (int j = 0; j < 8; ++j) {
            int o = oq * 8 + j;
            float sv = gma[o] * rsqrtf(var[o] + EPSV);
            float bb = (b1[o] - mu[o]) * sv + bta[o];
            tv16[j] = (_Float16)fmaxf(dot[j] * sv + bb, 0.f);
        }
        *(half8*)&t_lds[p * TSTH + oq * 8] = *(const half8*)tv16;
    }
    __syncthreads();

    // ---- phase 2: MFMA conv2 + depthwise aggregation ----
    const int q = p >> 4;          // lane quadrant
    const int r = p & 15;

    // B fragments: B[k][col=pixel], lane holds k = 8q..8q+7, col = 16nt + r
    half8 bfrag0 = *(const half8*)&t_lds[( 0 + r) * TSTH + q * 8];
    half8 bfrag1 = *(const half8*)&t_lds[(16 + r) * TSTH + q * 8];
    half8 bfrag2 = *(const half8*)&t_lds[(32 + r) * TSTH + q * 8];
    half8 bfrag3 = *(const half8*)&t_lds[(48 + r) * TSTH + q * 8];

    const int pb0 = (0 + (r >> 3)) * HALO + (r & 7);
    const int pb1 = (2 + (r >> 3)) * HALO + (r & 7);
    const int pb2 = (4 + (r >> 3)) * HALO + (r & 7);
    const int pb3 = (6 + (r >> 3)) * HALO + (r & 7);

    const f32x4 zero = {0.f, 0.f, 0.f, 0.f};

    #pragma unroll 1
    for (int lgi = 0; lgi < 2; ++lgi) {
        const int lg = oq * 2 + lgi;           // local group 0..7 (wave-uniform)
        const int g  = half * NSL + lg;        // global group 0..15
        const float* w2g = w2 + g * 49 * CRED;
        const float* b2g = b2 + g * 49;

        float acc[4][4];                       // [nt][channel], const-indexed only
        #pragma unroll
        for (int nt = 0; nt < 4; ++nt)
            #pragma unroll
            for (int c = 0; c < 4; ++c) acc[nt][c] = 0.f;

        // ---- mt = 0..2 : rows mt*16 + r <= 47 all real. ROLLED to cap liveness.
        #pragma clang loop unroll(disable)
        for (int mt = 0; mt < 3; ++mt) {
            half8 af;
            {
                const float* wr = w2g + (mt * 16 + r) * CRED + q * 8;
                float4 wa = *(const float4*)wr;
                float4 wb = *(const float4*)(wr + 4);
                af[0] = (_Float16)wa.x; af[1] = (_Float16)wa.y;
                af[2] = (_Float16)wa.z; af[3] = (_Float16)wa.w;
                af[4] = (_Float16)wb.x; af[5] = (_Float16)wb.y;
                af[6] = (_Float16)wb.z; af[7] = (_Float16)wb.w;
            }
            f32x4 d0 = __builtin_amdgcn_mfma_f32_16x16x32_f16(af, bfrag0, zero, 0, 0, 0);
            f32x4 d1 = __builtin_amdgcn_mfma_f32_16x16x32_f16(af, bfrag1, zero, 0, 0, 0);
            f32x4 d2 = __builtin_amdgcn_mfma_f32_16x16x32_f16(af, bfrag2, zero, 0, 0, 0);
            f32x4 d3 = __builtin_amdgcn_mfma_f32_16x16x32_f16(af, bfrag3, zero, 0, 0, 0);

            #pragma unroll
            for (int reg = 0; reg < 4; ++reg) {          // MUST stay fully unrolled
                const int tap = mt * 16 + q * 4 + reg;   // lane's tap, < 49
                const float bv = b2g[tap];
                const int di = (tap * 9363) >> 16;       // tap / 7
                const int tapoff = tap + 7 * di;         // di*14 + dj
                {
                    float wv = d0[reg] + bv;
                    int tp2 = pb0 + tapoff;
                    const float4 y4 = *(const float4*)&ytile[tp2 * NCH + (((lg + tp2) & 7) << 2)];
                    acc[0][0] += wv * y4.x; acc[0][1] += wv * y4.y;
                    acc[0][2] += wv * y4.z; acc[0][3] += wv * y4.w;
                }
                {
                    float wv = d1[reg] + bv;
                    int tp2 = pb1 + tapoff;
                    const float4 y4 = *(const float4*)&ytile[tp2 * NCH + (((lg + tp2) & 7) << 2)];
                    acc[1][0] += wv * y4.x; acc[1][1] += wv * y4.y;
                    acc[1][2] += wv * y4.z; acc[1][3] += wv * y4.w;
                }
                {
                    float wv = d2[reg] + bv;
                    int tp2 = pb2 + tapoff;
                    const float4 y4 = *(const float4*)&ytile[tp2 * NCH + (((lg + tp2) & 7) << 2)];
                    acc[2][0] += wv * y4.x; acc[2][1] += wv * y4.y;
                    acc[2][2] += wv * y4.z; acc[2][3] += wv * y4.w;
                }
                {
                    float wv = d3[reg] + bv;
                    int tp2 = pb3 + tapoff;
                    const float4 y4 = *(const float4*)&ytile[tp2 * NCH + (((lg + tp2) & 7) << 2)];
                    acc[3][0] += wv * y4.x; acc[3][1] += wv * y4.y;
                    acc[3][2] += wv * y4.z; acc[3][3] += wv * y4.w;
                }
            }
        }

        // ---- mt = 3 : only tap 48 real (lane r==0 holds row 48; q==0,reg==0 out)
        {
            half8 af;
            #pragma unroll
            for (int j = 0; j < 8; ++j) af[j] = (_Float16)0.f;
            if (r == 0) {
                const float* wr = w2g + 48 * CRED + q * 8;
                float4 wa = *(const float4*)wr;
                float4 wb = *(const float4*)(wr + 4);
                af[0] = (_Float16)wa.x; af[1] = (_Float16)wa.y;
                af[2] = (_Float16)wa.z; af[3] = (_Float16)wa.w;
                af[4] = (_Float16)wb.x; af[5] = (_Float16)wb.y;
                af[6] = (_Float16)wb.z; af[7] = (_Float16)wb.w;
            }
            f32x4 d0 = __builtin_amdgcn_mfma_f32_16x16x32_f16(af, bfrag0, zero, 0, 0, 0);
            f32x4 d1 = __builtin_amdgcn_mfma_f32_16x16x32_f16(af, bfrag1, zero, 0, 0, 0);
            f32x4 d2 = __builtin_amdgcn_mfma_f32_16x16x32_f16(af, bfrag2, zero, 0, 0, 0);
            f32x4 d3 = __builtin_amdgcn_mfma_f32_16x16x32_f16(af, bfrag3, zero, 0, 0, 0);

            const float bv = b2g[48];
            const int tapoff = 48 + 7 * 6;               // 90, uniform
            const bool live = (q == 0);
            {
                float wv = live ? (d0[0] + bv) : 0.f;
                int tp2 = pb0 + tapoff;
                const float4 y4 = *(const float4*)&ytile[tp2 * NCH + (((lg + tp2) & 7) << 2)];
                acc[0][0] += wv * y4.x; acc[0][1] += wv * y4.y;
                acc[0][2] += wv * y4.z; acc[0][3] += wv * y4.w;
            }
            {
                float wv = live ? (d1[0] + bv) : 0.f;
                int tp2 = pb1 + tapoff;
                const float4 y4 = *(const float4*)&ytile[tp2 * NCH + (((lg + tp2) & 7) << 2)];
                acc[1][0] += wv * y4.x; acc[1][1] += wv * y4.y;
                acc[1][2] += wv * y4.z; acc[1][3] += wv * y4.w;
            }
            {
                float wv = live ? (d2[0] + bv) : 0.f;
                int tp2 = pb2 + tapoff;
                const float4 y4 = *(const float4*)&ytile[tp2 * NCH + (((lg + tp2) & 7) << 2)];
                acc[2][0] += wv * y4.x; acc[2][1] += wv * y4.y;
                acc[2][2] += wv * y4.z; acc[2][3] += wv * y4.w;
            }
            {
                float wv = live ? (d3[0] + bv) : 0.f;
                int tp2 = pb3 + tapoff;
                const float4 y4 = *(const float4*)&ytile[tp2 * NCH + (((lg + tp2) & 7) << 2)];
                acc[3][0] += wv * y4.x; acc[3][1] += wv * y4.y;
                acc[3][2] += wv * y4.z; acc[3][3] += wv * y4.w;
            }
        }

        // reduce partial sums across quadrants (each quadrant covered a tap subset)
        #pragma unroll
        for (int nt = 0; nt < 4; ++nt)
            #pragma unroll
            for (int c = 0; c < 4; ++c) {
                float v = acc[nt][c];
                v += __shfl_xor(v, 16);
                v += __shfl_xor(v, 32);
                acc[nt][c] = v;
            }

        // lane p stores pixel p (= 16*q + r, i.e. nt = q)
        size_t ob = ((size_t)(b * C64 + g * GC4) << 14) + pix;
        #pragma unroll
        for (int c = 0; c < 4; ++c) {
            float s0 = (q & 1) ? acc[1][c] : acc[0][c];
            float s1 = (q & 1) ? acc[3][c] : acc[2][c];
            float vv = (q & 2) ? s1 : s0;
            out[ob + ((size_t)c << 14)] = vv;
        }
    }
}

extern "C" void kernel_launch(void* const* d_in, const int* in_sizes, int n_in,
                              void* d_out, int out_size, void* d_ws, size_t ws_size,
                              hipStream_t stream) {
    const float* x   = (const float*)d_in[0];
    const float* y   = (const float*)d_in[1];
    const float* w1  = (const float*)d_in[2];
    const float* b1  = (const float*)d_in[3];
    const float* gma = (const float*)d_in[4];
    const float* bta = (const float*)d_in[5];
    const float* mu  = (const float*)d_in[6];
    const float* var = (const float*)d_in[7];
    const float* w2  = (const float*)d_in[8];
    const float* b2  = (const float*)d_in[9];
    float* out = (float*)d_out;

    dim3 grid(128 / TILE, 128 / TILE, 8);   // 16 x 16 x (4 batch * 2 halves)
    dim3 block(256);
    hipLaunchKernelGGL(involution_mfma, grid, block, 0, stream,
                       x, y, w1, b1, gma, bta, mu, var, w2, b2, out);
}